// Round 8
// baseline (129.378 us; speedup 1.0000x reference)
//
#include <hip/hip_runtime.h>

#define NB   4
#define CH   256
#define CQK  32
#define NPOS 4096
#define KT   64
#define NCHK (NPOS / KT)     // 64
#define QT   64
#define LOG2E 1.4426950408889634f
#define THR2  10.0f   // defer-rescale threshold in log2 units (P <= 2^10)

typedef __attribute__((ext_vector_type(8))) short bf16x8;
typedef __attribute__((ext_vector_type(4))) float f32x4;
typedef unsigned short u16;
typedef unsigned int   u32;

static __device__ __forceinline__ u16 f2bf(float x) {
    union { float f; u32 u; } c; c.f = x;
    u32 u = c.u + 0x7FFFu + ((c.u >> 16) & 1u);
    return (u16)(u >> 16);
}
static __device__ __forceinline__ u32 pack2(float a, float b) {
    return (u32)f2bf(a) | ((u32)f2bf(b) << 16);
}
static __device__ __forceinline__ u32 cvtpk(float a, float b) {
    u32 r;
    asm("v_cvt_pk_bf16_f32 %0, %1, %2" : "=v"(r) : "v"(a), "v"(b));
    return r;
}
static __device__ __forceinline__ float exp2raw(float x) {
    float r;
    asm("v_exp_f32 %0, %1" : "=v"(r) : "v"(x));
    return r;
}

// ---------------------------------------------------------------------------
// W concat + bf16 convert (unchanged).
// ---------------------------------------------------------------------------
__global__ __launch_bounds__(256) void wcvt_kernel(
    const float* __restrict__ wq, const float* __restrict__ bq,
    const float* __restrict__ wk, const float* __restrict__ bk,
    const float* __restrict__ wv, const float* __restrict__ bv,
    u16* __restrict__ wb, float* __restrict__ bb)
{
    int idx = blockIdx.x * 256 + threadIdx.x;
    int e0 = idx * 4;
    const float* src; int off;
    if (e0 < 32 * 256)      { src = wq; off = e0; }
    else if (e0 < 64 * 256) { src = wk; off = e0 - 32 * 256; }
    else                    { src = wv; off = e0 - 64 * 256; }
    float4 v4 = *(const float4*)(src + off);
    *(uint2*)(wb + e0) = make_uint2(pack2(v4.x, v4.y), pack2(v4.z, v4.w));
    if (idx < 320) {
        float b = idx < 32 ? bq[idx] : (idx < 64 ? bk[idx - 32] : bv[idx - 64]);
        bb[idx] = b;
    }
}

// ---------------------------------------------------------------------------
// MFMA QKV projection (unchanged from R7; Q pre-scaled by log2e).
// ---------------------------------------------------------------------------
__global__ __launch_bounds__(256, 1) void qkv_proj_kernel(
    const float* __restrict__ x, const u16* __restrict__ wb, const float* __restrict__ bb,
    u16* __restrict__ qo, u16* __restrict__ ko, u16* __restrict__ vo)
{
    __shared__ u16 ldsx[32][264];
    const int t  = threadIdx.x;
    const int b  = blockIdx.x >> 7;
    const int n0 = (blockIdx.x & 127) * 32;
    const float* xb = x + (size_t)b * CH * NPOS;

    #pragma unroll
    for (int it = 0; it < 4; ++it) {
        int idx = it * 256 + t;
        int cp = idx >> 3;
        int n4 = (idx & 7) * 4;
        int c  = cp * 2;
        float4 a = *(const float4*)(xb + (size_t)c * NPOS + n0 + n4);
        float4 d = *(const float4*)(xb + (size_t)(c + 1) * NPOS + n0 + n4);
        #pragma unroll
        for (int i = 0; i < 4; ++i) {
            int n = n4 + i;
            u32 pv = pack2(((const float*)&a)[i], ((const float*)&d)[i]);
            *(u32*)((char*)ldsx + n * 528 + ((c * 2) ^ ((n & 7) << 4))) = pv;
        }
    }
    __syncthreads();

    const int w = t >> 6, lane = t & 63, g8 = lane >> 4, l16 = lane & 15;

    bf16x8 bf[2][8];
    #pragma unroll
    for (int ns = 0; ns < 2; ++ns) {
        int n = ns * 16 + l16;
        const char* rowp = (const char*)ldsx + n * 528;
        int swz = (n & 7) << 4;
        #pragma unroll
        for (int ks = 0; ks < 8; ++ks)
            bf[ns][ks] = *(const bf16x8*)(rowp + ((ks * 64 + g8 * 16) ^ swz));
    }

    u16* qdst = qo + (size_t)b * NPOS * CQK;
    u16* kdst = ko + (size_t)b * NPOS * CQK;
    u16* vdst = vo + (size_t)b * CH * NPOS;

    bf16x8 afA[8], afB[8];
    #pragma unroll
    for (int ks = 0; ks < 8; ++ks)
        afA[ks] = *(const bf16x8*)(wb + (w * 5 * 16 + l16) * 256 + ks * 32 + g8 * 8);

    #pragma unroll
    for (int j = 0; j < 5; ++j) {
        int ot = w * 5 + j;
        bf16x8* afc = (j & 1) ? afB : afA;
        bf16x8* afn = (j & 1) ? afA : afB;
        if (j + 1 < 5) {
            int otn = ot + 1;
            #pragma unroll
            for (int ks = 0; ks < 8; ++ks)
                afn[ks] = *(const bf16x8*)(wb + (otn * 16 + l16) * 256 + ks * 32 + g8 * 8);
        }
        f32x4 acc[2];
        acc[0] = (f32x4){0.f, 0.f, 0.f, 0.f};
        acc[1] = (f32x4){0.f, 0.f, 0.f, 0.f};
        #pragma unroll
        for (int ks = 0; ks < 8; ++ks) {
            acc[0] = __builtin_amdgcn_mfma_f32_16x16x32_bf16(afc[ks], bf[0][ks], acc[0], 0, 0, 0);
            acc[1] = __builtin_amdgcn_mfma_f32_16x16x32_bf16(afc[ks], bf[1][ks], acc[1], 0, 0, 0);
        }
        float4 bias = *(const float4*)(bb + ot * 16 + g8 * 4);

        if (ot < 4) {
            u16* dst = (ot < 2 ? qdst : kdst);
            float scl = (ot < 2) ? LOG2E : 1.0f;
            int ob = (ot & 1) * 16 + g8 * 4;
            #pragma unroll
            for (int ns = 0; ns < 2; ++ns) {
                int n = n0 + ns * 16 + l16;
                u32 lo = pack2((acc[ns][0] + bias.x) * scl, (acc[ns][1] + bias.y) * scl);
                u32 hi = pack2((acc[ns][2] + bias.z) * scl, (acc[ns][3] + bias.w) * scl);
                *(uint2*)(dst + (size_t)n * CQK + ob) = make_uint2(lo, hi);
            }
        } else {
            int orow = (ot - 4) * 16 + g8 * 4;
            const float* bp = (const float*)&bias;
            #pragma unroll
            for (int r = 0; r < 4; ++r)
                #pragma unroll
                for (int ns = 0; ns < 2; ++ns)
                    vdst[(size_t)(orow + r) * NPOS + n0 + ns * 16 + l16] =
                        f2bf(acc[ns][r] + bp[r]);
        }
    }
}

// ---------------------------------------------------------------------------
// Fused symmetric flash attention.  grid 256 (1 block/CU), 512 thr = 8 waves.
// Wave w = (strip s=w>>2 of 32 q) x (ch-quarter qd=w&3 of 64 ch): each wave
// does QK^T (swapped, K direct from L2 in regs) -> private softmax (defer-
// rescale, per-lane l partials) -> P via PRIVATE LDS scratch (same-wave,
// lgkmcnt only, no barrier) -> PV with V B-frags from a SHARED XOR-swizzled
// double-buffered LDS V tile (reg-staged; loads issued top-of-window,
// ds_writes end-of-window -> full-window latency slack).  QK duplicated x4
// across quarters (cheap).  ONE __syncthreads per window; no cross-wave
// softmax coupling at all.  Epilogue: per-wave l reduce + fused residual.
// LDS: V 2x32KB + P 8x4KB + SC 8x128B = 97KB.
// ---------------------------------------------------------------------------
#define VB_OFF  0        // 2 bufs x 256 ch x 128B = 65536
#define P_OFF   65536    // 8 waves x 32 q x 128B = 32768
#define SC_OFF  98304    // 8 waves x 128B
#define SMEMSZ  99328

__global__ __launch_bounds__(512, 1) void attn_kernel(
    const u16* __restrict__ q, const u16* __restrict__ k, const u16* __restrict__ v,
    const float* __restrict__ input, const float* __restrict__ gamma,
    float* __restrict__ out)
{
    __shared__ __align__(16) char smem[SMEMSZ];
    const int t = threadIdx.x;
    const int w = t >> 6;
    const int lane = t & 63;
    const int g8 = lane >> 4;
    const int l16 = lane & 15;
    const int l8 = lane & 7;      // stage: 16B col slot
    const int r8 = lane >> 3;     // stage: row within 8-ch group

    const int bid = blockIdx.x;
    const int b = (bid >> 1) & 3;
    const int tile = ((bid >> 3) << 1) | (bid & 1);
    const int i0 = tile * QT;

    const int s   = w >> 2;       // q strip (32 rows)
    const int qd  = w & 3;        // ch quarter
    const int ch0 = qd * 64;

    const u16* qb = q + (size_t)b * NPOS * CQK;
    const u16* kb = k + (size_t)b * NPOS * CQK;
    const u16* vb = v + (size_t)b * CH * NPOS;

    const int pswz = (l16 & 7) << 4;
    char* pw = smem + P_OFF + w * 4096;          // private P scratch
    char* scw = smem + SC_OFF + w * 128;         // private sc/l scratch

    // loop-invariant Q B-frags (rows i0+s*32+qt*16+l16, d g8*8..+7)
    bf16x8 qf[2];
    #pragma unroll
    for (int qt = 0; qt < 2; ++qt)
        qf[qt] = *(const bf16x8*)(qb + (size_t)(i0 + s * 32 + qt * 16 + l16) * CQK + g8 * 8);

    // K A-frags, window 0 (keys kt*16+l16, d g8*8..+7)
    bf16x8 kc[4];
    #pragma unroll
    for (int kt = 0; kt < 4; ++kt)
        kc[kt] = *(const bf16x8*)(kb + (size_t)(kt * 16 + l16) * CQK + g8 * 8);

    // stage V window 0 -> buf0 (wave stages ch rows [w*32, w*32+32))
    {
        uint4 vst[4];
        #pragma unroll
        for (int i = 0; i < 4; ++i) {
            int ch = w * 32 + i * 8 + r8;
            vst[i] = *(const uint4*)(vb + (size_t)ch * NPOS + l8 * 8);
        }
        #pragma unroll
        for (int i = 0; i < 4; ++i) {
            int ch = w * 32 + i * 8 + r8;
            *(uint4*)(smem + VB_OFF + ch * 128 + ((l8 * 16) ^ ((ch & 7) << 4))) = vst[i];
        }
    }
    __syncthreads();

    f32x4 acc[2][4];
    #pragma unroll
    for (int qt = 0; qt < 2; ++qt)
        #pragma unroll
        for (int ct = 0; ct < 4; ++ct)
            acc[qt][ct] = (f32x4){0.f, 0.f, 0.f, 0.f};
    float mrun[2] = {-__builtin_inff(), -__builtin_inff()};
    float lrun[2] = {0.f, 0.f};

    for (int jc = 0; jc < NCHK; ++jc) {
        const char* vbuf = smem + VB_OFF + (jc & 1) * 32768;
        const bool more = (jc + 1 < NCHK);
        const int j0n = (jc + 1) * KT;

        // issue next window's V stage loads FIRST (full-window slack)
        uint4 vst[4];
        if (more) {
            #pragma unroll
            for (int i = 0; i < 4; ++i) {
                int ch = w * 32 + i * 8 + r8;
                vst[i] = *(const uint4*)(vb + (size_t)ch * NPOS + j0n + l8 * 8);
            }
        }

        // QK^T (swapped): S[key kt*16+g8*4+r][query qt*16+l16]
        f32x4 z = {0.f, 0.f, 0.f, 0.f};
        f32x4 sS[2][4];
        #pragma unroll
        for (int qt = 0; qt < 2; ++qt)
            #pragma unroll
            for (int kt = 0; kt < 4; ++kt)
                sS[qt][kt] = __builtin_amdgcn_mfma_f32_16x16x32_bf16(kc[kt], qf[qt], z, 0, 0, 0);

        // in-place K reload for next window
        if (more) {
            #pragma unroll
            for (int kt = 0; kt < 4; ++kt)
                kc[kt] = *(const bf16x8*)(kb + (size_t)(j0n + kt * 16 + l16) * CQK + g8 * 8);
        }

        // softmax: per-lane local max, wave-collective defer check
        float lmax[2];
        #pragma unroll
        for (int qt = 0; qt < 2; ++qt) {
            float a0 = fmaxf(fmaxf(sS[qt][0][0], sS[qt][0][1]), fmaxf(sS[qt][0][2], sS[qt][0][3]));
            float a1 = fmaxf(fmaxf(sS[qt][1][0], sS[qt][1][1]), fmaxf(sS[qt][1][2], sS[qt][1][3]));
            float a2 = fmaxf(fmaxf(sS[qt][2][0], sS[qt][2][1]), fmaxf(sS[qt][2][2], sS[qt][2][3]));
            float a3 = fmaxf(fmaxf(sS[qt][3][0], sS[qt][3][1]), fmaxf(sS[qt][3][2], sS[qt][3][3]));
            lmax[qt] = fmaxf(fmaxf(a0, a1), fmaxf(a2, a3));
        }
        bool pred = (lmax[0] > mrun[0] + THR2) || (lmax[1] > mrun[1] + THR2);
        if (__any(pred)) {                       // rare slow path
            #pragma unroll
            for (int qt = 0; qt < 2; ++qt) {
                float mx = lmax[qt];
                mx = fmaxf(mx, __shfl_xor(mx, 16));
                mx = fmaxf(mx, __shfl_xor(mx, 32));
                mx = fmaxf(mx, mrun[qt]);
                float sc = exp2raw(mrun[qt] - mx);   // exp2(-inf)=0 first time
                mrun[qt] = mx;
                lrun[qt] *= sc;
                if (g8 == 0)
                    *(float*)(scw + (qt * 16 + l16) * 4) = sc;
            }
            #pragma unroll
            for (int qt = 0; qt < 2; ++qt) {
                f32x4 ss = *(const f32x4*)(scw + (qt * 16 + g8 * 4) * 4);
                #pragma unroll
                for (int ct = 0; ct < 4; ++ct) acc[qt][ct] *= ss;
            }
        }

        // P = exp2(S - m) -> private LDS (row q, keys linear, XOR-swizzled)
        #pragma unroll
        for (int qt = 0; qt < 2; ++qt) {
            char* prow = pw + (qt * 16 + l16) * 128;
            float lsum = 0.f;
            #pragma unroll
            for (int kt = 0; kt < 4; ++kt) {
                float p0 = exp2raw(sS[qt][kt][0] - mrun[qt]);
                float p1 = exp2raw(sS[qt][kt][1] - mrun[qt]);
                float p2 = exp2raw(sS[qt][kt][2] - mrun[qt]);
                float p3 = exp2raw(sS[qt][kt][3] - mrun[qt]);
                lsum += (p0 + p1) + (p2 + p3);
                *(uint2*)(prow + ((kt * 32 + g8 * 8) ^ pswz)) =
                    make_uint2(cvtpk(p0, p1), cvtpk(p2, p3));
            }
            lrun[qt] += lsum;                    // per-lane partial only
        }

        // P A-frags back (same wave: compiler inserts lgkmcnt, no barrier)
        bf16x8 pa[2][2];
        #pragma unroll
        for (int qt = 0; qt < 2; ++qt)
            #pragma unroll
            for (int kc2 = 0; kc2 < 2; ++kc2)
                pa[qt][kc2] = *(const bf16x8*)(pw + (qt * 16 + l16) * 128 +
                                               ((kc2 * 64 + g8 * 16) ^ pswz));

        // PV: V B-frags from shared LDS tile (row ch, 2-way bank = free)
        __builtin_amdgcn_s_setprio(1);
        #pragma unroll
        for (int ct = 0; ct < 4; ++ct) {
            const char* vrow = vbuf + (ch0 + ct * 16 + l16) * 128;
            bf16x8 vf0 = *(const bf16x8*)(vrow + ((g8 * 16) ^ pswz));
            bf16x8 vf1 = *(const bf16x8*)(vrow + ((64 + g8 * 16) ^ pswz));
            #pragma unroll
            for (int qt = 0; qt < 2; ++qt) {
                acc[qt][ct] = __builtin_amdgcn_mfma_f32_16x16x32_bf16(pa[qt][0], vf0, acc[qt][ct], 0, 0, 0);
                acc[qt][ct] = __builtin_amdgcn_mfma_f32_16x16x32_bf16(pa[qt][1], vf1, acc[qt][ct], 0, 0, 0);
            }
        }
        __builtin_amdgcn_s_setprio(0);

        // write staged V for next window into the other buffer
        if (more) {
            char* vB = smem + VB_OFF + ((jc + 1) & 1) * 32768;
            #pragma unroll
            for (int i = 0; i < 4; ++i) {
                int ch = w * 32 + i * 8 + r8;
                *(uint4*)(vB + ch * 128 + ((l8 * 16) ^ ((ch & 7) << 4))) = vst[i];
            }
        }
        __syncthreads();
    }

    // epilogue: finalize l per wave, fused residual store
    f32x4 rl[2];
    #pragma unroll
    for (int qt = 0; qt < 2; ++qt) {
        float lv = lrun[qt];
        lv += __shfl_xor(lv, 16);
        lv += __shfl_xor(lv, 32);
        if (g8 == 0)
            *(float*)(scw + (qt * 16 + l16) * 4) = lv;
    }
    #pragma unroll
    for (int qt = 0; qt < 2; ++qt) {
        f32x4 lv = *(const f32x4*)(scw + (qt * 16 + g8 * 4) * 4);
        f32x4 one = {1.f, 1.f, 1.f, 1.f};
        rl[qt] = one / lv;
    }
    const float gmm = gamma[0];
    const float* inb = input + (size_t)b * CH * NPOS;
    float* ob = out + (size_t)b * CH * NPOS;

    #pragma unroll
    for (int qt = 0; qt < 2; ++qt) {
        #pragma unroll
        for (int ct = 0; ct < 4; ++ct) {
            f32x4 val = acc[qt][ct] * rl[qt];
            int ch = ch0 + ct * 16 + l16;
            size_t gi = (size_t)ch * NPOS + i0 + s * 32 + qt * 16 + g8 * 4;
            float4 in4 = *(const float4*)(inb + gi);
            float4 r4;
            r4.x = gmm * val[0] + in4.x;
            r4.y = gmm * val[1] + in4.y;
            r4.z = gmm * val[2] + in4.z;
            r4.w = gmm * val[3] + in4.w;
            *(float4*)(ob + gi) = r4;
        }
    }
}

// ---------------------------------------------------------------------------
extern "C" void kernel_launch(void* const* d_in, const int* in_sizes, int n_in,
                              void* d_out, int out_size, void* d_ws, size_t ws_size,
                              hipStream_t stream) {
    const float* input = (const float*)d_in[0];
    const float* wq    = (const float*)d_in[1];
    const float* bq    = (const float*)d_in[2];
    const float* wk    = (const float*)d_in[3];
    const float* bk    = (const float*)d_in[4];
    const float* wv    = (const float*)d_in[5];
    const float* bv    = (const float*)d_in[6];
    const float* gamma = (const float*)d_in[7];
    float* out = (float*)d_out;

    const size_t qk_elems = (size_t)NB * NPOS * CQK;   // 524288
    const size_t v_elems  = (size_t)NB * CH * NPOS;    // 4194304
    const size_t w_elems  = 320 * 256;                 // 81920
    size_t need = (2 * qk_elems + v_elems + w_elems) * sizeof(u16) + 320 * sizeof(float);
    if (ws_size < need) return;

    u16* qw = (u16*)d_ws;
    u16* kw = qw + qk_elems;
    u16* vw = kw + qk_elems;
    u16* wb = vw + v_elems;
    float* bbuf = (float*)(wb + w_elems);

    wcvt_kernel<<<dim3(80), dim3(256), 0, stream>>>(wq, bq, wk, bk, wv, bv, wb, bbuf);
    qkv_proj_kernel<<<dim3(NB * (NPOS / 32)), dim3(256), 0, stream>>>(input, wb, bbuf, qw, kw, vw);
    attn_kernel<<<dim3(NB * (NPOS / QT)), dim3(512), 0, stream>>>(qw, kw, vw, input, gamma, out);
}